// Round 7
// baseline (271.561 us; speedup 1.0000x reference)
//
#include <hip/hip_runtime.h>
#include <stdint.h>

typedef unsigned short u16;
typedef short short8 __attribute__((ext_vector_type(8)));
typedef short short4v __attribute__((ext_vector_type(4)));
typedef float float4v __attribute__((ext_vector_type(4)));
typedef uint32_t uint2v __attribute__((ext_vector_type(2)));

#define HW 4096
#define SCL 0.18033688011112042f   /* 0.125 * log2(e) */

// async global->LDS DMA: per-lane global addr, LDS dest = wave-uniform base + lane*16
#define GLOAD_LDS(g, l) __builtin_amdgcn_global_load_lds( \
    (const __attribute__((address_space(1))) void*)(g),   \
    (__attribute__((address_space(3))) void*)(l), 16, 0, 0)

static __device__ __forceinline__ u16 f2bf(float f) {
  union { float f; uint32_t u; } v; v.f = f;
  uint32_t r = v.u + 0x7fffu + ((v.u >> 16) & 1u);
  return (u16)(r >> 16);
}
// fast round (ties-away) — fine for p >= 0
static __device__ __forceinline__ uint32_t f2bf_u32(float f) {
  union { float f; uint32_t u; } v; v.f = f;
  return (v.u + 0x8000u) >> 16;
}

// ---- kernel 1: x [4,256,4096] f32 -> Xtp [4,66,66,256] bf16 (spatially padded; halo pre-zeroed)
__global__ __launch_bounds__(256) void k_xt(const float* __restrict__ x, u16* __restrict__ Xtp) {
  __shared__ float t[32][33];
  const int b = blockIdx.z, c0 = blockIdx.y * 32, p0 = blockIdx.x * 32;
  const int tid = threadIdx.x;
  const int l8 = tid >> 5, lp = tid & 31;
#pragma unroll
  for (int i = 0; i < 4; i++) {
    int c = l8 + i * 8;
    t[c][lp] = x[(size_t)(b * 256 + c0 + c) * HW + p0 + lp];
  }
  __syncthreads();
#pragma unroll
  for (int i = 0; i < 4; i++) {
    int p = l8 + i * 8;
    int pp = p0 + p;
    int y = pp >> 6, xx = pp & 63;
    Xtp[((size_t)(b * 66 + y + 1) * 66 + (xx + 1)) * 256 + c0 + lp] = f2bf(t[lp][p]);
  }
}

// ---- kernel 2: repack weights -> Wt [9][384][256] bf16 (ci contiguous), bcat[384] f32
__global__ __launch_bounds__(256) void k_wprep(const float* __restrict__ qw, const float* __restrict__ qb,
    const float* __restrict__ kw, const float* __restrict__ kb,
    const float* __restrict__ vw, const float* __restrict__ vb,
    u16* __restrict__ Wt, float* __restrict__ bcat) {
  int tid = blockIdx.x * 256 + threadIdx.x;
  if (tid < 9 * 384 * 256) {
    int ci = tid & 255;
    int n = (tid >> 8) % 384;
    int off = tid / (384 * 256);
    float val;
    if (n < 64)       val = qw[(size_t)n * 2304 + ci * 9 + off];
    else if (n < 128) val = kw[(size_t)(n - 64) * 2304 + ci * 9 + off];
    else              val = vw[(size_t)(n - 128) * 2304 + ci * 9 + off];
    Wt[tid] = f2bf(val);
  }
  if (tid < 384) bcat[tid] = (tid < 64) ? qb[tid] : (tid < 128) ? kb[tid - 64] : vb[tid - 128];
}

// ---- kernel 3: fused QKV conv, now with DMA double-buffered staging.
// 9 shifted GEMMs, 128 pos x 128 outch per block, BK=32, 72 iters,
// ONE barrier per iter: stage(next->buf^1 via global_load_lds) -> compute(buf)
// -> sync (drains DMA; protects buf^1 WAR). LDS unpadded, 16B-chunk XOR
// swizzle (chunk ^ row&3) applied on the global-address side -> even banks.
__global__ __launch_bounds__(256) void k_conv(const u16* __restrict__ Xtp,
    const u16* __restrict__ Wt, const float* __restrict__ bcat,
    u16* __restrict__ Qt, u16* __restrict__ Kt, u16* __restrict__ Vcf) {
  __shared__ __align__(16) u16 Als[2][128 * 32];   // 8 KB per buf
  __shared__ __align__(16) u16 Bls[2][128 * 32];
  const int tid = threadIdx.x;
  const int b = blockIdx.z, ntile = blockIdx.y;
  const int p0 = blockIdx.x * 128, n0 = ntile * 128;
  const int w = tid >> 6, lane = tid & 63, l16 = lane & 15, quad = lane >> 4;
  const int mw = (w & 1) * 64, nw = (w >> 1) * 64;
  // DMA lane map: 16 rows x 4 chunks(16B) per wave-DMA; 2 DMAs each for A,B
  const int lr = lane >> 2, cx = (lane & 3) ^ (lr & 3);
  const u16* ag[2]; const u16* bg[2];
#pragma unroll
  for (int g = 0; g < 2; g++) {
    const int row = w * 32 + g * 16 + lr;
    const int pos = p0 + row, py = pos >> 6, px = pos & 63;
    ag[g] = Xtp + ((size_t)(b * 66 + py) * 66 + px) * 256 + cx * 8;
    bg[g] = Wt + (size_t)(n0 + row) * 256 + cx * 8;
  }
  const int ldd = w * 1024;                // u16 dest offset (+g*512)
  const int fca = (quad ^ (l16 & 3)) * 8;  // swizzled frag chunk

  float4v acc[4][4];
  const float4v zz = {0.f, 0.f, 0.f, 0.f};
#pragma unroll
  for (int i = 0; i < 4; i++)
#pragma unroll
    for (int j = 0; j < 4; j++) acc[i][j] = zz;

  // prologue: stage ks=0 (off=0 -> dy=dx=0, cb=0) into buf 0
#pragma unroll
  for (int g = 0; g < 2; g++) {
    GLOAD_LDS(ag[g], &Als[0][ldd + g * 512]);
    GLOAD_LDS(bg[g], &Bls[0][ldd + g * 512]);
  }
  __syncthreads();

  for (int ks = 0; ks < 72; ks++) {
    const int buf = ks & 1;
    if (ks + 1 < 72) {
      const int ksn = ks + 1, off = ksn >> 3, cb = ksn & 7;
      const int dy = off / 3, dx = off - dy * 3;
      const int aoff = (dy * 66 + dx) * 256 + cb * 32;
      const size_t boff = (size_t)off * 98304 + cb * 32;
#pragma unroll
      for (int g = 0; g < 2; g++) {
        GLOAD_LDS(ag[g] + aoff, &Als[buf ^ 1][ldd + g * 512]);
        GLOAD_LDS(bg[g] + boff, &Bls[buf ^ 1][ldd + g * 512]);
      }
    }
    short8 af[4], bfv[4];
#pragma unroll
    for (int mt = 0; mt < 4; mt++) af[mt] = *(const short8*)&Als[buf][(mw + mt * 16 + l16) * 32 + fca];
#pragma unroll
    for (int nt = 0; nt < 4; nt++) bfv[nt] = *(const short8*)&Bls[buf][(nw + nt * 16 + l16) * 32 + fca];
    if (ntile == 0) {
#pragma unroll
      for (int mt = 0; mt < 4; mt++)
#pragma unroll
        for (int nt = 0; nt < 4; nt++)
          acc[mt][nt] = __builtin_amdgcn_mfma_f32_16x16x32_bf16(bfv[nt], af[mt], acc[mt][nt], 0, 0, 0);
    } else {
#pragma unroll
      for (int mt = 0; mt < 4; mt++)
#pragma unroll
        for (int nt = 0; nt < 4; nt++)
          acc[mt][nt] = __builtin_amdgcn_mfma_f32_16x16x32_bf16(af[mt], bfv[nt], acc[mt][nt], 0, 0, 0);
    }
    __syncthreads();
  }

  if (ntile == 0) {
#pragma unroll
    for (int mt = 0; mt < 4; mt++) {
      const int p = p0 + mw + mt * 16 + l16;
#pragma unroll
      for (int nt = 0; nt < 4; nt++) {
        const int nb = nw + nt * 16 + quad * 4;
        short4v o;
#pragma unroll
        for (int r = 0; r < 4; r++) o[r] = (short)f2bf(acc[mt][nt][r] + bcat[nb + r]);
        u16* dst = (nb < 64) ? (Qt + (size_t)(b * HW + p) * 64 + nb)
                             : (Kt + (size_t)(b * HW + p) * 64 + (nb - 64));
        *(short4v*)dst = o;
      }
    }
  } else {
#pragma unroll
    for (int mt = 0; mt < 4; mt++) {
      const int pb = p0 + mw + mt * 16 + quad * 4;
#pragma unroll
      for (int nt = 0; nt < 4; nt++) {
        const int c = (ntile - 1) * 128 + nw + nt * 16 + l16;
        const float bias = bcat[128 + c];
        short4v o;
#pragma unroll
        for (int r = 0; r < 4; r++) o[r] = (short)f2bf(acc[mt][nt][r] + bias);
        *(short4v*)(Vcf + (size_t)(b * 256 + c) * HW + pb) = o;
      }
    }
  }
}

// ---- kernel 4: redistributed flash attention. Grid (128 i-tiles of 32, 4 b),
// block = 32 q x 256 c, j-tile 32, 128 iters, 2 barriers/iter.
// Wave (qt=w&1, jh=w>>1): QK^T for its 16q x 16j quadrant -> shared P[32][40];
// after B1 every wave computes PV for its own 64-channel slice over all 32 q
// (V read once per block; exp computed once per (i,j)). K/V DMA-double-
// buffered, staged at iter top (drained at B1, ~300cyc slack); all LDS
// b128 accesses XOR-swizzled to even 8-dword/bank distribution.
__global__ __launch_bounds__(256, 2) void k_attn(const u16* __restrict__ Qt,
    const u16* __restrict__ Kt, const u16* __restrict__ Vcf, float* __restrict__ out) {
  __shared__ __align__(16) u16 Kls[2][32 * 64];    // 8 KB  [j][d] swizzled
  __shared__ __align__(16) u16 Vls[2][256 * 32];   // 32 KB [c][j] swizzled
  __shared__ __align__(16) u16 Pls[32 * 40];       // 2.5 KB [i][j], pad 40
  __shared__ float Lsh[2][32];
  const int tid = threadIdx.x;
  const int b = blockIdx.y, i0 = blockIdx.x * 32;
  const int w = tid >> 6, lane = tid & 63, l16 = lane & 15, quad = lane >> 4;
  const int qt = w & 1, jh = w >> 1;

  const u16* Kb = Kt + (size_t)b * HW * 64;
  const u16* Vb = Vcf + (size_t)b * 256 * HW;

  // K DMA (1/wave): rows w*8+lr8 (128B rows, 8 chunks), chunk (lane&7)^lr8
  const int lr8 = lane >> 3;
  const u16* kg = Kb + (size_t)(w * 8 + lr8) * 64 + ((lane & 7) ^ lr8) * 8;
  const int kld = w * 512;
  // V DMA (4/wave): rows w*64+g*16+lr4 (64B rows, 4 chunks), chunk (lane&3)^(lr4&3)
  const int lr4 = lane >> 2;
  const u16* vg = Vb + (size_t)(w * 64 + lr4) * HW + ((lane & 3) ^ (lr4 & 3)) * 8;
  const int vld = w * 2048;

  // Q frag (B-operand) for this wave's q-tile: B[k=d=quad*8+t][n=i=l16]
  short8 qf[2];
  {
    const u16* qp = Qt + (size_t)(b * HW + i0 + qt * 16 + l16) * 64 + quad * 8;
    qf[0] = *(const short8*)qp;
    qf[1] = *(const short8*)(qp + 32);
  }

  // frag LDS offsets (u16 units)
  const int kro0 = (jh * 16 + l16) * 64 + ((quad    ) ^ (l16 & 7)) * 8;
  const int kro1 = (jh * 16 + l16) * 64 + ((quad + 4) ^ (l16 & 7)) * 8;
  const int vro  = (quad ^ (l16 & 3)) * 8;
  const int pwo  = (qt * 16 + l16) * 40 + jh * 16 + quad * 4;
  const int pro  = l16 * 40 + quad * 8;     // + q2*640

  float4v of[4][2];
  const float4v zz = {0.f, 0.f, 0.f, 0.f};
#pragma unroll
  for (int ct = 0; ct < 4; ct++) { of[ct][0] = zz; of[ct][1] = zz; }
  float lsum = 0.f;

  // prologue: stage tile 0 into buf 0
  GLOAD_LDS(kg, &Kls[0][kld]);
#pragma unroll
  for (int g = 0; g < 4; g++) GLOAD_LDS(vg + (size_t)g * 16 * HW, &Vls[0][vld + g * 512]);
  __syncthreads();

  for (int jt = 0; jt < 128; jt++) {
    const int buf = jt & 1;
    const int jn = ((jt + 1) & 127) * 32;
    // ---- stage next tile into buf^1 (safe: all PV reads of buf^1 ended at B2(jt-1))
    GLOAD_LDS(kg + (size_t)jn * 64, &Kls[buf ^ 1][kld]);
#pragma unroll
    for (int g = 0; g < 4; g++)
      GLOAD_LDS(vg + (size_t)g * 16 * HW + jn, &Vls[buf ^ 1][vld + g * 512]);

    // ---- S^T quadrant: D[m=j_local][n=i], A=K[j][d], B=Q
    float4v sf = zz;
    {
      short8 k0 = *(const short8*)&Kls[buf][kro0];
      short8 k1 = *(const short8*)&Kls[buf][kro1];
      sf = __builtin_amdgcn_mfma_f32_16x16x32_bf16(k0, qf[0], sf, 0, 0, 0);
      sf = __builtin_amdgcn_mfma_f32_16x16x32_bf16(k1, qf[1], sf, 0, 0, 0);
    }

    // ---- P = exp2(S*SCL) (no-max softmax; scale-invariant after 1/l)
    float p0 = exp2f(sf[0] * SCL);
    float p1 = exp2f(sf[1] * SCL);
    float p2 = exp2f(sf[2] * SCL);
    float p3 = exp2f(sf[3] * SCL);
    float rs = (p0 + p1) + (p2 + p3);
    uint2v pd;
    pd[0] = f2bf_u32(p0) | (f2bf_u32(p1) << 16);
    pd[1] = f2bf_u32(p2) | (f2bf_u32(p3) << 16);
    *(uint2v*)&Pls[pwo] = pd;
    rs += __shfl_xor(rs, 16);
    rs += __shfl_xor(rs, 32);
    lsum += rs;                    // l[i=i0+qt*16+l16] over jh-half, lane-aligned

    __syncthreads();               // B1: P visible; K/V DMA(jt+1) drained

    // ---- PV: wave's 64-channel slice over all 32 q.  A=V[c][j], B=P[i][j]
    {
      short8 pf0 = *(const short8*)&Pls[pro];
      short8 pf1 = *(const short8*)&Pls[pro + 640];
#pragma unroll
      for (int ct = 0; ct < 4; ct++) {
        short8 vf = *(const short8*)&Vls[buf][(w * 64 + ct * 16 + l16) * 32 + vro];
        of[ct][0] = __builtin_amdgcn_mfma_f32_16x16x32_bf16(vf, pf0, of[ct][0], 0, 0, 0);
        of[ct][1] = __builtin_amdgcn_mfma_f32_16x16x32_bf16(vf, pf1, of[ct][1], 0, 0, 0);
      }
    }
    __syncthreads();               // B2: PV reads of buf/P done
  }

  if (lane < 16) Lsh[jh][qt * 16 + lane] = lsum;
  __syncthreads();
  float linv[2];
#pragma unroll
  for (int q2 = 0; q2 < 2; q2++)
    linv[q2] = 1.0f / (Lsh[0][q2 * 16 + l16] + Lsh[1][q2 * 16 + l16]);

#pragma unroll
  for (int ct = 0; ct < 4; ct++)
#pragma unroll
    for (int q2 = 0; q2 < 2; q2++)
#pragma unroll
      for (int r = 0; r < 4; r++)
        out[(size_t)(b * 256 + w * 64 + ct * 16 + quad * 4 + r) * HW + i0 + q2 * 16 + l16] =
            of[ct][q2][r] * linv[q2];
}

extern "C" void kernel_launch(void* const* d_in, const int* in_sizes, int n_in,
                              void* d_out, int out_size, void* d_ws, size_t ws_size,
                              hipStream_t stream) {
  const float* x  = (const float*)d_in[0];
  const float* qw = (const float*)d_in[1];
  const float* qb = (const float*)d_in[2];
  const float* kw = (const float*)d_in[3];
  const float* kb = (const float*)d_in[4];
  const float* vw = (const float*)d_in[5];
  const float* vb = (const float*)d_in[6];
  float* out = (float*)d_out;
  char* ws = (char*)d_ws;
  u16*   Xtp = (u16*)(ws);
  u16*   Wt  = (u16*)(ws + 8921088);
  float* bc  = (float*)(ws + 10690560);
  u16*   Qt  = (u16*)(ws + 10692096);
  u16*   Kt  = (u16*)(ws + 12789248);
  u16*   Vcf = (u16*)(ws + 14886400);

  hipMemsetAsync(Xtp, 0, 8921088, stream);  // zero the spatial halo
  k_xt  <<<dim3(128, 8, 4), 256, 0, stream>>>(x, Xtp);
  k_wprep<<<3456, 256, 0, stream>>>(qw, qb, kw, kb, vw, vb, Wt, bc);
  k_conv<<<dim3(32, 3, 4), 256, 0, stream>>>(Xtp, Wt, bc, Qt, Kt, Vcf);
  k_attn<<<dim3(128, 4), 256, 0, stream>>>(Qt, Kt, Vcf, out);
}